// Round 1
// baseline (357.086 us; speedup 1.0000x reference)
//
#include <hip/hip_runtime.h>
#include <cstdint>
#include <cstddef>

#define DM 2048
#define TT 2048
#define BB 2
#define HQ 16
#define HKV 4
#define HD 128
#define WIN 1024
#define META 128

typedef _Float16 f16;
using f16x8 = __attribute__((ext_vector_type(8))) f16;
using f32x4 = __attribute__((ext_vector_type(4))) float;

#define MFMA16(a, b, c) __builtin_amdgcn_mfma_f32_16x16x32_f16(a, b, c, 0, 0, 0)

// ---------------- fp32 -> fp16 convert (vectorized) ----------------
__global__ __launch_bounds__(256) void k_cvt_f16(const float* __restrict__ in,
                                                 f16* __restrict__ out, int n8) {
  int i = blockIdx.x * 256 + threadIdx.x;
  if (i >= n8) return;
  const float4* pin = (const float4*)in;
  float4 a = pin[2 * i], b = pin[2 * i + 1];
  f16x8 o = {(f16)a.x, (f16)a.y, (f16)a.z, (f16)a.w,
             (f16)b.x, (f16)b.y, (f16)b.z, (f16)b.w};
  *(f16x8*)&out[(size_t)8 * i] = o;
}

// ------------- transpose + convert: in fp32 [K][N] -> out f16 [N][K] -------------
__global__ __launch_bounds__(256) void k_tr_cvt(const float* __restrict__ in,
                                                f16* __restrict__ out, int N, int ldout) {
  __shared__ float tile[32][33];
  int n0 = blockIdx.x * 32, k0 = blockIdx.y * 32;
  int tx = threadIdx.x, ty = threadIdx.y;
#pragma unroll
  for (int r = 0; r < 32; r += 8) tile[ty + r][tx] = in[(size_t)(k0 + ty + r) * N + n0 + tx];
  __syncthreads();
#pragma unroll
  for (int r = 0; r < 32; r += 8)
    out[(size_t)(n0 + ty + r) * ldout + k0 + tx] = (f16)tile[tx][ty + r];
}

// ---------------- MFMA GEMM: C[M,N] = A[M,K] * BT[N,K]^T ----------------
template <int N_, bool OUT_F16>
__global__ __launch_bounds__(256) void k_gemm(const f16* __restrict__ A,
                                              const f16* __restrict__ BT,
                                              void* __restrict__ Cp, int M, int K) {
  constexpr int BK = 64;
  __shared__ alignas(16) f16 As[128][72];
  __shared__ alignas(16) f16 Bs[128][72];
  constexpr int NT = N_ / 128;
  int bid = blockIdx.x;
  int m0 = (bid / NT) * 128, n0 = (bid % NT) * 128;
  int tid = threadIdx.x;
  int lane = tid & 63, w = tid >> 6;
  int wm = (w >> 1) * 64, wn = (w & 1) * 64;
  int g = lane >> 4, c = lane & 15;
  int sr = tid >> 3, sc = (tid & 7) * 8;
  f32x4 acc[4][4] = {};
  for (int k0 = 0; k0 < K; k0 += BK) {
#pragma unroll
    for (int i = 0; i < 4; i++) {
      int r = sr + 32 * i;
      *(uint4*)&As[r][sc] = *(const uint4*)&A[(size_t)(m0 + r) * K + k0 + sc];
      *(uint4*)&Bs[r][sc] = *(const uint4*)&BT[(size_t)(n0 + r) * K + k0 + sc];
    }
    __syncthreads();
#pragma unroll
    for (int ks = 0; ks < 2; ks++) {
      f16x8 af[4], bf[4];
#pragma unroll
      for (int mm = 0; mm < 4; mm++) af[mm] = *(const f16x8*)&As[wm + mm * 16 + c][ks * 32 + g * 8];
#pragma unroll
      for (int nn = 0; nn < 4; nn++) bf[nn] = *(const f16x8*)&Bs[wn + nn * 16 + c][ks * 32 + g * 8];
#pragma unroll
      for (int mm = 0; mm < 4; mm++)
#pragma unroll
        for (int nn = 0; nn < 4; nn++)
          acc[mm][nn] = MFMA16(af[mm], bf[nn], acc[mm][nn]);
    }
    __syncthreads();
  }
  int gg = lane >> 4, cc = lane & 15;
#pragma unroll
  for (int mm = 0; mm < 4; mm++)
#pragma unroll
    for (int nn = 0; nn < 4; nn++)
#pragma unroll
      for (int r = 0; r < 4; r++) {
        size_t row = m0 + wm + mm * 16 + gg * 4 + r;
        size_t col = n0 + wn + nn * 16 + cc;
        float v = acc[mm][nn][r];
        if constexpr (OUT_F16)
          ((f16*)Cp)[row * N_ + col] = (f16)v;
        else
          ((float*)Cp)[row * N_ + col] = v;
      }
}

// ---------------- RMSNorm + RoPE + relayout ----------------
__global__ __launch_bounds__(256) void k_norm_rope(const f16* __restrict__ qkv,
                                                   const int* __restrict__ pos_ids,
                                                   const float* __restrict__ qw,
                                                   const float* __restrict__ kw,
                                                   f16* __restrict__ Qo, f16* __restrict__ Ko,
                                                   f16* __restrict__ Vo) {
  int bt = blockIdx.x;
  int b = bt >> 11, t = bt & 2047;
  int tid = threadIdx.x, w = tid >> 6, lane = tid & 63;
  const f16* row = qkv + (size_t)bt * 3072;
  if (tid < 64) {
    f16x8 v = *(const f16x8*)&row[2560 + tid * 8];
    int hkv = tid >> 4, d = (tid & 15) * 8;
    *(f16x8*)&Vo[(((size_t)b * HKV + hkv) * TT + t) * HD + d] = v;
  }
  float pq = (float)pos_ids[t];
  float pk = (float)t;
  // inv_freq = 10000^(-lane/64) = exp(-lane * ln(10000)/64)
  float inv = expf(-(float)lane * 0.14391156831212787f);
  for (int hi = w; hi < 20; hi += 4) {
    bool isq = hi < 16;
    int off = isq ? hi * 128 : 2048 + (hi - 16) * 128;
    float x1 = (float)row[off + 2 * lane];
    float x2 = (float)row[off + 2 * lane + 1];
    float ss = x1 * x1 + x2 * x2;
#pragma unroll
    for (int o = 1; o < 64; o <<= 1) ss += __shfl_xor(ss, o);
    float rms = rsqrtf(ss * (1.0f / 128.0f) + 1e-6f);
    const float* wt = isq ? qw : kw;
    float n1 = x1 * rms * wt[2 * lane], n2 = x2 * rms * wt[2 * lane + 1];
    float pos = isq ? pq : pk;
    float ang = pos * inv;
    float sn = sinf(ang), cs = cosf(ang);
    f16 r1 = (f16)(n1 * cs - n2 * sn), r2 = (f16)(n1 * sn + n2 * cs);
    if (isq) {
      f16* dst = Qo + (((size_t)b * HQ + hi) * TT + t) * HD;
      dst[2 * lane] = r1;
      dst[2 * lane + 1] = r2;
    } else {
      f16* dst = Ko + (((size_t)b * HKV + (hi - 16)) * TT + t) * HD;
      dst[2 * lane] = r1;
      dst[2 * lane + 1] = r2;
    }
  }
}

// ---------------- flash attention with meta tokens + sliding window ----------------
__global__ __launch_bounds__(256) void k_attn(const f16* __restrict__ Q,
                                              const f16* __restrict__ Kc,
                                              const f16* __restrict__ Vc,
                                              f16* __restrict__ Oa) {
  int qt = blockIdx.x, h = blockIdx.y, b = blockIdx.z;
  int hkv = h >> 2;
  int q0 = qt * 64;
  int tid = threadIdx.x;
  int w = tid >> 6, lane = tid & 63, g = lane >> 4, c = lane & 15;
  __shared__ alignas(16) f16 Ks[32][136];
  __shared__ alignas(16) f16 VTs[128][40];
  __shared__ alignas(16) f16 Ps[4][16][40];
  const f16* Qp = Q + (((size_t)b * HQ + h) * TT + q0 + w * 16 + c) * HD;
  f16x8 qf[4];
#pragma unroll
  for (int s = 0; s < 4; s++) qf[s] = *(const f16x8*)&Qp[s * 32 + g * 8];
  f32x4 o[8] = {};
  float m_r[4] = {-1e30f, -1e30f, -1e30f, -1e30f};
  float l_r[4] = {0.f, 0.f, 0.f, 0.f};
  const f16* Kb = Kc + ((size_t)b * HKV + hkv) * TT * HD;
  const f16* Vb = Vc + ((size_t)b * HKV + hkv) * TT * HD;
  int wlo = max(q0 - WIN + 1, META) & ~31;
  int nwin = (wlo <= q0 + 63) ? (q0 + 64 - wlo) / 32 : 0;
  int ntiles = 4 + nwin;
  const float scale = 0.08838834764831845f;
  for (int ti = 0; ti < ntiles; ti++) {
    int k0 = (ti < 4) ? ti * 32 : wlo + (ti - 4) * 32;
    __syncthreads();  // previous iteration's PV done with Ks/VTs
#pragma unroll
    for (int i = 0; i < 2; i++) {
      int gk = tid + i * 256;
      int kr = gk >> 4, kc = (gk & 15) * 8;
      *(uint4*)&Ks[kr][kc] = *(const uint4*)&Kb[(size_t)(k0 + kr) * HD + kc];
      int vcg = gk >> 5, vr = gk & 31;
      uint4 vv = *(const uint4*)&Vb[(size_t)(k0 + vr) * HD + vcg * 8];
      const f16* pv = (const f16*)&vv;
#pragma unroll
      for (int j = 0; j < 8; j++) VTs[vcg * 8 + j][vr] = pv[j];
    }
    __syncthreads();
    // S = Q K^T for two 16-key subtiles
    f32x4 s[2];
#pragma unroll
    for (int kk = 0; kk < 2; kk++) {
      f32x4 a = {};
#pragma unroll
      for (int sd = 0; sd < 4; sd++) {
        f16x8 kf = *(const f16x8*)&Ks[kk * 16 + c][sd * 32 + g * 8];
        a = MFMA16(qf[sd], kf, a);
      }
      s[kk] = a;
    }
    float p[2][4];
    float alpha[4];
#pragma unroll
    for (int r = 0; r < 4; r++) {
      int q = q0 + w * 16 + g * 4 + r;
      int wstart = max(q - WIN + 1, META);
      float mx = -1e30f;
#pragma unroll
      for (int kk = 0; kk < 2; kk++) {
        int k = k0 + kk * 16 + c;
        bool ok = (k < META) || ((k >= wstart) && (k <= q));
        float v = ok ? s[kk][r] * scale : -1e30f;
        p[kk][r] = v;
        mx = fmaxf(mx, v);
      }
#pragma unroll
      for (int off = 1; off < 16; off <<= 1) mx = fmaxf(mx, __shfl_xor(mx, off));
      float mn = fmaxf(m_r[r], mx);
      alpha[r] = __expf(m_r[r] - mn);
      m_r[r] = mn;
      float rs = 0.f;
#pragma unroll
      for (int kk = 0; kk < 2; kk++) {
        float e = __expf(p[kk][r] - mn);
        p[kk][r] = e;
        rs += e;
      }
#pragma unroll
      for (int off = 1; off < 16; off <<= 1) rs += __shfl_xor(rs, off);
      l_r[r] = l_r[r] * alpha[r] + rs;
    }
#pragma unroll
    for (int n = 0; n < 8; n++)
#pragma unroll
      for (int r = 0; r < 4; r++) o[n][r] *= alpha[r];
    // P -> LDS (bf16 round-trip to MFMA A-operand layout)
#pragma unroll
    for (int kk = 0; kk < 2; kk++)
#pragma unroll
      for (int r = 0; r < 4; r++) Ps[w][g * 4 + r][kk * 16 + c] = (f16)p[kk][r];
    __syncthreads();
    f16x8 pf = *(const f16x8*)&Ps[w][c][g * 8];
#pragma unroll
    for (int n = 0; n < 8; n++) {
      f16x8 vf = *(const f16x8*)&VTs[n * 16 + c][g * 8];
      o[n] = MFMA16(pf, vf, o[n]);
    }
  }
#pragma unroll
  for (int n = 0; n < 8; n++)
#pragma unroll
    for (int r = 0; r < 4; r++) {
      int q = q0 + w * 16 + g * 4 + r;
      float v = o[n][r] / l_r[r];
      Oa[((size_t)b * TT + q) * DM + h * HD + n * 16 + c] = (f16)v;
    }
}

extern "C" void kernel_launch(void* const* d_in, const int* in_sizes, int n_in,
                              void* d_out, int out_size, void* d_ws, size_t ws_size,
                              hipStream_t stream) {
  const float* hidden = (const float*)d_in[0];
  const int* pos = (const int*)d_in[1];
  const float* Wq = (const float*)d_in[2];
  const float* Wk = (const float*)d_in[3];
  const float* Wv = (const float*)d_in[4];
  const float* Wo = (const float*)d_in[5];
  const float* qw = (const float*)d_in[6];
  const float* kw = (const float*)d_in[7];
  float* out = (float*)d_out;

  char* p = (char*)d_ws;
  auto take = [&](size_t n) {
    void* r = (void*)p;
    p += (n + 255) & ~(size_t)255;
    return r;
  };
  f16* Xb = (f16*)take((size_t)4096 * 2048 * 2);
  f16* WqkvT = (f16*)take((size_t)3072 * 2048 * 2);
  f16* WoT = (f16*)take((size_t)2048 * 2048 * 2);
  f16* QKVb = (f16*)take((size_t)4096 * 3072 * 2);
  f16* Qr = (f16*)take((size_t)BB * HQ * TT * HD * 2);
  f16* Kr = (f16*)take((size_t)BB * HKV * TT * HD * 2);
  f16* Vr = (f16*)take((size_t)BB * HKV * TT * HD * 2);
  f16* Attn = (f16*)take((size_t)4096 * 2048 * 2);

  dim3 tb(32, 8);
  k_cvt_f16<<<4096, 256, 0, stream>>>(hidden, Xb, 1048576);
  k_tr_cvt<<<dim3(64, 64), tb, 0, stream>>>(Wq, WqkvT, 2048, 2048);
  k_tr_cvt<<<dim3(16, 64), tb, 0, stream>>>(Wk, WqkvT + (size_t)2048 * 2048, 512, 2048);
  k_tr_cvt<<<dim3(16, 64), tb, 0, stream>>>(Wv, WqkvT + (size_t)2560 * 2048, 512, 2048);
  k_tr_cvt<<<dim3(64, 64), tb, 0, stream>>>(Wo, WoT, 2048, 2048);
  k_gemm<3072, true><<<768, 256, 0, stream>>>(Xb, WqkvT, QKVb, 4096, 2048);
  k_norm_rope<<<4096, 256, 0, stream>>>(QKVb, pos, qw, kw, Qr, Kr, Vr);
  k_attn<<<dim3(32, 16, 2), 256, 0, stream>>>(Qr, Kr, Vr, Attn);
  k_gemm<2048, false><<<512, 256, 0, stream>>>(Attn, WoT, out, 4096, 2048);
}

// Round 3
// 274.714 us; speedup vs baseline: 1.2998x; 1.2998x over previous
//
#include <hip/hip_runtime.h>
#include <cstdint>
#include <cstddef>

#define DM 2048
#define TT 2048
#define BB 2
#define HQ 16
#define HKV 4
#define HD 128

typedef _Float16 f16;
using f16x8 = __attribute__((ext_vector_type(8))) f16;
using f32x4 = __attribute__((ext_vector_type(4))) float;
using f32x16 = __attribute__((ext_vector_type(16))) float;

#define MFMA16(a, b, c) __builtin_amdgcn_mfma_f32_16x16x32_f16(a, b, c, 0, 0, 0)
#define MFMA32(a, b, c) __builtin_amdgcn_mfma_f32_32x32x16_f16(a, b, c, 0, 0, 0)

static __device__ __forceinline__ float fast_exp2(float x) {
#if __has_builtin(__builtin_amdgcn_exp2f)
  return __builtin_amdgcn_exp2f(x);
#else
  return exp2f(x);
#endif
}

static __device__ __forceinline__ uint32_t cvt_pk_u32(float a, float b) {
  auto h2 = __builtin_amdgcn_cvt_pkrtz(a, b);  // __fp16 ext_vector(2)
  return __builtin_bit_cast(uint32_t, h2);
}

// ---------------- fp32 -> fp16 convert (vectorized) ----------------
__global__ __launch_bounds__(256) void k_cvt_f16(const float* __restrict__ in,
                                                 f16* __restrict__ out, int n8) {
  int i = blockIdx.x * 256 + threadIdx.x;
  if (i >= n8) return;
  const float4* pin = (const float4*)in;
  float4 a = pin[2 * i], b = pin[2 * i + 1];
  f16x8 o = {(f16)a.x, (f16)a.y, (f16)a.z, (f16)a.w,
             (f16)b.x, (f16)b.y, (f16)b.z, (f16)b.w};
  *(f16x8*)&out[(size_t)8 * i] = o;
}

// ------------- transpose + convert: in fp32 [K][N] -> out f16 [N][K] -------------
__global__ __launch_bounds__(256) void k_tr_cvt(const float* __restrict__ in,
                                                f16* __restrict__ out, int N, int ldout) {
  __shared__ float tile[32][33];
  int n0 = blockIdx.x * 32, k0 = blockIdx.y * 32;
  int tx = threadIdx.x, ty = threadIdx.y;
#pragma unroll
  for (int r = 0; r < 32; r += 8) tile[ty + r][tx] = in[(size_t)(k0 + ty + r) * N + n0 + tx];
  __syncthreads();
#pragma unroll
  for (int r = 0; r < 32; r += 8)
    out[(size_t)(n0 + ty + r) * ldout + k0 + tx] = (f16)tile[tx][ty + r];
}

// ---------------- MFMA GEMM: C[M,N] = A[M,K] * BT[N,K]^T ----------------
template <int N_, bool OUT_F16>
__global__ __launch_bounds__(256) void k_gemm(const f16* __restrict__ A,
                                              const f16* __restrict__ BT,
                                              void* __restrict__ Cp, int M, int K) {
  constexpr int BK = 64;
  __shared__ alignas(16) f16 As[128][72];
  __shared__ alignas(16) f16 Bs[128][72];
  constexpr int NT = N_ / 128;
  int bid = blockIdx.x;
  int m0 = (bid / NT) * 128, n0 = (bid % NT) * 128;
  int tid = threadIdx.x;
  int lane = tid & 63, w = tid >> 6;
  int wm = (w >> 1) * 64, wn = (w & 1) * 64;
  int g = lane >> 4, c = lane & 15;
  int sr = tid >> 3, sc = (tid & 7) * 8;
  f32x4 acc[4][4] = {};
  for (int k0 = 0; k0 < K; k0 += BK) {
#pragma unroll
    for (int i = 0; i < 4; i++) {
      int r = sr + 32 * i;
      *(uint4*)&As[r][sc] = *(const uint4*)&A[(size_t)(m0 + r) * K + k0 + sc];
      *(uint4*)&Bs[r][sc] = *(const uint4*)&BT[(size_t)(n0 + r) * K + k0 + sc];
    }
    __syncthreads();
#pragma unroll
    for (int ks = 0; ks < 2; ks++) {
      f16x8 af[4], bf[4];
#pragma unroll
      for (int mm = 0; mm < 4; mm++) af[mm] = *(const f16x8*)&As[wm + mm * 16 + c][ks * 32 + g * 8];
#pragma unroll
      for (int nn = 0; nn < 4; nn++) bf[nn] = *(const f16x8*)&Bs[wn + nn * 16 + c][ks * 32 + g * 8];
#pragma unroll
      for (int mm = 0; mm < 4; mm++)
#pragma unroll
        for (int nn = 0; nn < 4; nn++)
          acc[mm][nn] = MFMA16(af[mm], bf[nn], acc[mm][nn]);
    }
    __syncthreads();
  }
  int gg = lane >> 4, cc = lane & 15;
#pragma unroll
  for (int mm = 0; mm < 4; mm++)
#pragma unroll
    for (int nn = 0; nn < 4; nn++)
#pragma unroll
      for (int r = 0; r < 4; r++) {
        size_t row = m0 + wm + mm * 16 + gg * 4 + r;
        size_t col = n0 + wn + nn * 16 + cc;
        float v = acc[mm][nn][r];
        if constexpr (OUT_F16)
          ((f16*)Cp)[row * N_ + col] = (f16)v;
        else
          ((float*)Cp)[row * N_ + col] = v;
      }
}

// ---------------- RMSNorm + RoPE + relayout (Q, K only) ----------------
__global__ __launch_bounds__(256) void k_norm_rope(const f16* __restrict__ qkv,
                                                   const int* __restrict__ pos_ids,
                                                   const float* __restrict__ qw,
                                                   const float* __restrict__ kw,
                                                   f16* __restrict__ Qo, f16* __restrict__ Ko) {
  int bt = blockIdx.x;
  int b = bt >> 11, t = bt & 2047;
  int tid = threadIdx.x, w = tid >> 6, lane = tid & 63;
  const f16* row = qkv + (size_t)bt * 3072;
  float pq = (float)pos_ids[t];
  float pk = (float)t;
  float inv = expf(-(float)lane * 0.14391156831212787f);
  for (int hi = w; hi < 20; hi += 4) {
    bool isq = hi < 16;
    int off = isq ? hi * 128 : 2048 + (hi - 16) * 128;
    float x1 = (float)row[off + 2 * lane];
    float x2 = (float)row[off + 2 * lane + 1];
    float ss = x1 * x1 + x2 * x2;
#pragma unroll
    for (int o = 1; o < 64; o <<= 1) ss += __shfl_xor(ss, o);
    float rms = rsqrtf(ss * (1.0f / 128.0f) + 1e-6f);
    const float* wt = isq ? qw : kw;
    float n1 = x1 * rms * wt[2 * lane], n2 = x2 * rms * wt[2 * lane + 1];
    float pos = isq ? pq : pk;
    float ang = pos * inv;
    float sn = sinf(ang), cs = cosf(ang);
    f16 r1 = (f16)(n1 * cs - n2 * sn), r2 = (f16)(n1 * sn + n2 * cs);
    if (isq) {
      f16* dst = Qo + (((size_t)b * HQ + hi) * TT + t) * HD;
      dst[2 * lane] = r1;
      dst[2 * lane + 1] = r2;
    } else {
      f16* dst = Ko + (((size_t)b * HKV + (hi - 16)) * TT + t) * HD;
      dst[2 * lane] = r1;
      dst[2 * lane + 1] = r2;
    }
  }
}

// ------- V transpose: from QKV buffer cols [2560..3072) -> Vt[b][hkv][d][t] -------
__global__ __launch_bounds__(256) void k_trV(const f16* __restrict__ qkv,
                                             f16* __restrict__ Vt) {
  __shared__ f16 tile[32][34];
  int t0 = blockIdx.x * 32, d0 = blockIdx.y * 32;
  int bh = blockIdx.z;
  int b = bh >> 2, hkv = bh & 3;
  int tx = threadIdx.x, ty = threadIdx.y;
  const f16* src = qkv + (size_t)b * 2048 * 3072 + 2560 + hkv * 128;
#pragma unroll
  for (int r = 0; r < 32; r += 8)
    tile[ty + r][tx] = src[(size_t)(t0 + ty + r) * 3072 + d0 + tx];
  __syncthreads();
  f16* dst = Vt + ((size_t)bh * HD + d0) * TT + t0;
#pragma unroll
  for (int r = 0; r < 32; r += 8)
    dst[(size_t)(ty + r) * TT + tx] = tile[tx][ty + r];
}

// ---------------- attention: 4 waves x 32q, 64-key tiles, swapped QK^T ----------------
__global__ __launch_bounds__(256, 2) void k_attn2(const f16* __restrict__ Q,
                                                  const f16* __restrict__ Kc,
                                                  const f16* __restrict__ Vt,
                                                  f16* __restrict__ Oa) {
  __shared__ alignas(16) char KsC[64 * 256];   // K tile: 64 keys x 128 d, swizzled
  __shared__ alignas(16) char VsC[128 * 128];  // V^T tile: 128 d x 64 keys, swizzled
  int qt = blockIdx.x, h = blockIdx.y, b = blockIdx.z;
  int q0 = qt * 128, hkv = h >> 2;
  int tid = threadIdx.x;
  int w = tid >> 6, lane = tid & 63, ln = lane & 31, hi = lane >> 5;
  const f16* Kb = Kc + ((size_t)b * HKV + hkv) * TT * HD;
  const f16* Vb = Vt + ((size_t)b * HKV + hkv) * (size_t)HD * TT;
  int q = q0 + w * 32 + ln;
  const f16* Qp = Q + (((size_t)b * HQ + h) * TT + q) * HD + hi * 8;
  f16x8 qf[8];
#pragma unroll
  for (int st = 0; st < 8; st++) qf[st] = *(const f16x8*)&Qp[st * 16];
  f32x16 o[4] = {};
  float lsum = 0.f;
  int kr = tid >> 2, kqb = (tid & 3) * 64;  // K stage: row, byte base in row
  int vr = tid >> 1, vqb = (tid & 1) * 64;  // V stage
  int kswz = (kr & 7) << 4, vswz = (vr & 7) << 4;
  int kfswz = (ln & 7) << 4;

  int k0max = (q0 + 127) & ~63;
  int wlo = (q0 - 1023 > 128) ? ((q0 - 1023) & ~63) : 128;
  int nw = (k0max >= wlo) ? ((k0max - wlo) >> 6) + 1 : 0;
  int ntiles = 2 + nw;
  int qw = q0 + w * 32;

  const float C1 = 0.12751791217100872f;  // (1/sqrt(128)) * log2(e)
  const float C2 = 5.7707801635534255f;   // 4.0 * log2(e)  (fixed softmax shift)

  uint4 kreg[4], vreg[4];
  {  // prologue: load + store tile 0 (k0 = 0)
    const char* kp = (const char*)(Kb + (size_t)kr * HD);
#pragma unroll
    for (int i = 0; i < 4; i++) kreg[i] = *(const uint4*)(kp + kqb + i * 16);
    const char* vp = (const char*)(Vb + (size_t)vr * TT);
#pragma unroll
    for (int i = 0; i < 4; i++) vreg[i] = *(const uint4*)(vp + vqb + i * 16);
    char* kd = KsC + kr * 256;
#pragma unroll
    for (int i = 0; i < 4; i++) *(uint4*)(kd + ((kqb + i * 16) ^ kswz)) = kreg[i];
    char* vd = VsC + vr * 128;
#pragma unroll
    for (int i = 0; i < 4; i++) *(uint4*)(vd + ((vqb + i * 16) ^ vswz)) = vreg[i];
  }
  __syncthreads();

  for (int ti = 0; ti < ntiles; ti++) {
    int k0 = (ti < 2) ? ti * 64 : wlo + (ti - 2) * 64;
    bool havenext = (ti + 1 < ntiles);
    if (havenext) {  // issue next tile's global loads now; latency hides under MFMA
      int k0n = (ti + 1 < 2) ? (ti + 1) * 64 : wlo + (ti - 1) * 64;
      const char* kp = (const char*)(Kb + (size_t)(k0n + kr) * HD);
#pragma unroll
      for (int i = 0; i < 4; i++) kreg[i] = *(const uint4*)(kp + kqb + i * 16);
      const char* vp = (const char*)(Vb + (size_t)vr * TT + (size_t)k0n);
#pragma unroll
      for (int i = 0; i < 4; i++) vreg[i] = *(const uint4*)(vp + vqb + i * 16);
    }
    bool needmask = false;
    if (ti >= 2) {
      int wsmax = qw + 31 - 1023;
      if (wsmax < 128) wsmax = 128;
      needmask = !((k0 + 63 <= qw) && (k0 >= wsmax));
    }
    f16x8 pa[2][2];
#pragma unroll
    for (int ksub = 0; ksub < 2; ksub++) {
      f32x16 s = {};
      const char* krow = KsC + (ksub * 32 + ln) * 256;
#pragma unroll
      for (int st = 0; st < 8; st++) {
        f16x8 kf = *(const f16x8*)(krow + ((st * 32 + hi * 16) ^ kfswz));
        s = MFMA32(kf, qf[st], s);  // S^T: lane col = q, regs = keys
      }
      int qmk = q - (k0 + ksub * 32 + 4 * hi);
      float pr[16];
#pragma unroll
      for (int r = 0; r < 16; r++) {
        float e = fast_exp2(s[r] * C1 - C2);
        if (needmask) {
          int kk = (r & 3) + 8 * (r >> 2);
          e = ((uint32_t)(qmk - kk) < 1024u) ? e : 0.0f;
        }
        lsum += e;
        pr[r] = e;
      }
      uint32_t c[8];
#pragma unroll
      for (int i = 0; i < 8; i++) c[i] = cvt_pk_u32(pr[2 * i], pr[2 * i + 1]);
      // permlane32_swap: exchange halves with partner lane (+/-32) to build A-frags
      uint32_t a0 = c[0], a1 = c[2];
      asm("v_permlane32_swap_b32 %0, %1" : "+v"(a0), "+v"(a1));
      uint32_t b0 = c[1], b1 = c[3];
      asm("v_permlane32_swap_b32 %0, %1" : "+v"(b0), "+v"(b1));
      union U4a { uint32_t u[4]; f16x8 v; } t0;
      t0.u[0] = a0; t0.u[1] = b0; t0.u[2] = a1; t0.u[3] = b1;
      pa[ksub][0] = t0.v;
      uint32_t a2 = c[4], a3 = c[6];
      asm("v_permlane32_swap_b32 %0, %1" : "+v"(a2), "+v"(a3));
      uint32_t b2 = c[5], b3 = c[7];
      asm("v_permlane32_swap_b32 %0, %1" : "+v"(b2), "+v"(b3));
      union U4b { uint32_t u[4]; f16x8 v; } t1;
      t1.u[0] = a2; t1.u[1] = b2; t1.u[2] = a3; t1.u[3] = b3;
      pa[ksub][1] = t1.v;
    }
    // PV: o[q][d] += P[q][k] V[k][d]
#pragma unroll
    for (int dsub = 0; dsub < 4; dsub++) {
      const char* vrow = VsC + (dsub * 32 + ln) * 128;
#pragma unroll
      for (int ksub = 0; ksub < 2; ksub++)
#pragma unroll
        for (int st2 = 0; st2 < 2; st2++) {
          f16x8 vf = *(const f16x8*)(vrow + ((ksub * 64 + st2 * 32 + hi * 16) ^ kfswz));
          o[dsub] = MFMA32(pa[ksub][st2], vf, o[dsub]);
        }
    }
    __syncthreads();
    if (havenext) {
      char* kd = KsC + kr * 256;
#pragma unroll
      for (int i = 0; i < 4; i++) *(uint4*)(kd + ((kqb + i * 16) ^ kswz)) = kreg[i];
      char* vd = VsC + vr * 128;
#pragma unroll
      for (int i = 0; i < 4; i++) *(uint4*)(vd + ((vqb + i * 16) ^ vswz)) = vreg[i];
    }
    __syncthreads();
  }
  // epilogue: finish l, scale, store
  lsum += __shfl_xor(lsum, 32);
  float rl[16];
#pragma unroll
  for (int r = 0; r < 16; r++) {
    int row = (r & 3) + 8 * (r >> 2) + 4 * hi;
    float lv = __shfl(lsum, row);
    rl[r] = 1.0f / lv;
  }
#pragma unroll
  for (int r = 0; r < 16; r++) {
    int row = (r & 3) + 8 * (r >> 2) + 4 * hi;
    size_t base = ((size_t)b * TT + q0 + w * 32 + row) * DM + (size_t)h * HD + ln;
#pragma unroll
    for (int dsub = 0; dsub < 4; dsub++)
      Oa[base + dsub * 32] = (f16)(o[dsub][r] * rl[r]);
  }
}

extern "C" void kernel_launch(void* const* d_in, const int* in_sizes, int n_in,
                              void* d_out, int out_size, void* d_ws, size_t ws_size,
                              hipStream_t stream) {
  const float* hidden = (const float*)d_in[0];
  const int* pos = (const int*)d_in[1];
  const float* Wq = (const float*)d_in[2];
  const float* Wk = (const float*)d_in[3];
  const float* Wv = (const float*)d_in[4];
  const float* Wo = (const float*)d_in[5];
  const float* qw = (const float*)d_in[6];
  const float* kw = (const float*)d_in[7];
  float* out = (float*)d_out;

  char* p = (char*)d_ws;
  auto take = [&](size_t n) {
    void* r = (void*)p;
    p += (n + 255) & ~(size_t)255;
    return r;
  };
  f16* Xb = (f16*)take((size_t)4096 * 2048 * 2);
  f16* WqkvT = (f16*)take((size_t)3072 * 2048 * 2);
  f16* WoT = (f16*)take((size_t)2048 * 2048 * 2);
  f16* QKVb = (f16*)take((size_t)4096 * 3072 * 2);
  f16* Qr = (f16*)take((size_t)BB * HQ * TT * HD * 2);
  f16* Kr = (f16*)take((size_t)BB * HKV * TT * HD * 2);
  f16* Vt = (f16*)take((size_t)BB * HKV * TT * HD * 2);
  f16* Attn = (f16*)take((size_t)4096 * 2048 * 2);

  dim3 tb(32, 8);
  k_cvt_f16<<<4096, 256, 0, stream>>>(hidden, Xb, 1048576);
  k_tr_cvt<<<dim3(64, 64), tb, 0, stream>>>(Wq, WqkvT, 2048, 2048);
  k_tr_cvt<<<dim3(16, 64), tb, 0, stream>>>(Wk, WqkvT + (size_t)2048 * 2048, 512, 2048);
  k_tr_cvt<<<dim3(16, 64), tb, 0, stream>>>(Wv, WqkvT + (size_t)2560 * 2048, 512, 2048);
  k_tr_cvt<<<dim3(64, 64), tb, 0, stream>>>(Wo, WoT, 2048, 2048);
  k_gemm<3072, true><<<768, 256, 0, stream>>>(Xb, WqkvT, QKVb, 4096, 2048);
  k_norm_rope<<<4096, 256, 0, stream>>>(QKVb, pos, qw, kw, Qr, Kr);
  k_trV<<<dim3(64, 4, 8), tb, 0, stream>>>(QKVb, Vt);
  k_attn2<<<dim3(16, 16, 2), 256, 0, stream>>>(Qr, Kr, Vt, Attn);
  k_gemm<2048, false><<<512, 256, 0, stream>>>(Attn, WoT, out, 4096, 2048);
}